// Round 1
// baseline (280.727 us; speedup 1.0000x reference)
//
#include <hip/hip_runtime.h>
#include <cmath>

#define BB 8
#define NN 2048
#define CC 512
#define HH 8
#define DD 64
#define FF 1536
#define MM (BB*NN)   // 16384

typedef _Float16 half_t;
typedef __attribute__((ext_vector_type(8))) _Float16 half8;
typedef __attribute__((ext_vector_type(4))) _Float16 half4;
typedef __attribute__((ext_vector_type(4))) float floatx4;
typedef __attribute__((ext_vector_type(16))) float floatx16;
typedef __attribute__((ext_vector_type(4))) float fx4;

#define LOG2E 1.44269504088896f

// async global->LDS, 16 B per lane; LDS dest must be wave-uniform base (+lane*16)
typedef const __attribute__((address_space(1))) unsigned int* gas_ptr;
typedef __attribute__((address_space(3))) unsigned int* las_ptr;
__device__ __forceinline__ void gld16(const half_t* g, half_t* l) {
  __builtin_amdgcn_global_load_lds((gas_ptr)g, (las_ptr)l, 16, 0, 0);
}

// ---------------------------------------------------------------------------
// fp32 -> fp16 convert (8 elems/thread)
// ---------------------------------------------------------------------------
__global__ __launch_bounds__(256) void cvt_kernel(
    const float* __restrict__ s, half_t* __restrict__ d, int n8) {
  int i = blockIdx.x * 256 + threadIdx.x;
  if (i < n8) {
    float4 a = ((const float4*)s)[i * 2], b = ((const float4*)s)[i * 2 + 1];
    half8 h;
    h[0] = (half_t)a.x; h[1] = (half_t)a.y; h[2] = (half_t)a.z; h[3] = (half_t)a.w;
    h[4] = (half_t)b.x; h[5] = (half_t)b.y; h[6] = (half_t)b.z; h[7] = (half_t)b.w;
    ((half8*)d)[i] = h;
  }
}

// ---------------------------------------------------------------------------
// Kernel 1: qkv = x @ W_qkv^T  (fp16 MFMA, 128x128 tile, BK=32, 4 waves)
// Fused epilogue: RoPE (+ q scale incl. log2e) -> Qh/Kh fp16 (B,H,N,D);
// V -> LDS transpose -> Vt fp16 (B,H,D,N).   [unchanged this round]
// ---------------------------------------------------------------------------
__global__ __launch_bounds__(256) void qkv_mfma_kernel(
    const half_t* __restrict__ Ah,   // (16384, 512)
    const half_t* __restrict__ Bh,   // (1536, 512)
    const int*   __restrict__ ncp,
    half_t* __restrict__ Qh, half_t* __restrict__ Kh, half_t* __restrict__ Vt)
{
  __shared__ union {
    struct { half_t A[128 * 32]; half_t B[128 * 32]; } s;   // 16 KB
    half_t T[4][64 * 68];                                   // 34.8 KB (V epilogue)
  } sm;

  const int tid  = threadIdx.x;
  const int wave = tid >> 6, lane = tid & 63;
  const int L15  = lane & 15, quad = lane >> 4;
  const int wm = (wave & 1) * 64, wn = (wave >> 1) * 64;
  const int m0 = blockIdx.x * 128;
  const int f0 = blockIdx.y * 128;

  const int srow = lane >> 2;            // 0..15
  const int scolh = (lane & 3) * 8;      // half offset within row
  const half_t* Ag = Ah + (size_t)(m0 + wave * 16 + srow) * CC + scolh;
  const half_t* Bg = Bh + (size_t)(f0 + wave * 16 + srow) * CC + scolh;
  half_t* Al = &sm.s.A[(wave * 16) * 32];
  half_t* Bl = &sm.s.B[(wave * 16) * 32];

  floatx4 acc[4][4];
#pragma unroll
  for (int i = 0; i < 4; ++i)
#pragma unroll
    for (int j = 0; j < 4; ++j) acc[i][j] = (floatx4){0.f, 0.f, 0.f, 0.f};

  for (int k0 = 0; k0 < CC; k0 += 32) {
    __syncthreads();
    gld16(Ag + k0,            Al);
    gld16(Ag + k0 + 64 * CC,  Al + 64 * 32);
    gld16(Bg + k0,            Bl);
    gld16(Bg + k0 + 64 * CC,  Bl + 64 * 32);
    __syncthreads();
    half8 af[4], bf[4];
#pragma unroll
    for (int mi = 0; mi < 4; ++mi)
      af[mi] = *(const half8*)&sm.s.A[(wm + mi * 16 + L15) * 32 + quad * 8];
#pragma unroll
    for (int ni = 0; ni < 4; ++ni)
      bf[ni] = *(const half8*)&sm.s.B[(wn + ni * 16 + L15) * 32 + quad * 8];
#pragma unroll
    for (int mi = 0; mi < 4; ++mi)
#pragma unroll
      for (int ni = 0; ni < 4; ++ni)
        acc[mi][ni] = __builtin_amdgcn_mfma_f32_16x16x32_f16(af[mi], bf[ni], acc[mi][ni], 0, 0, 0);
  }

  const int which = f0 >> 9;         // block-uniform (128 | 512)
  const int b     = m0 >> 11;        // block-uniform
  const int n_base = (m0 & 2047) + wm;

  if (which < 2) {
    const int nc = *ncp;
    half_t* dst = which ? Kh : Qh;
    const float qscale = which ? 1.0f : (0.125f * LOG2E);
#pragma unroll
    for (int ni = 0; ni < 4; ++ni) {
      const int f = f0 + wn + ni * 16 + L15;
      const int h = (f >> 6) & 7;
      const int d = f & 63;
      const float invf = __powf(10000.0f, -(float)(d & ~1) * (1.0f / 64.0f));
      const float sgn = (d & 1) ? 1.0f : -1.0f;
#pragma unroll
      for (int mi = 0; mi < 4; ++mi)
#pragma unroll
        for (int r = 0; r < 4; ++r) {
          const int n = n_base + mi * 16 + quad * 4 + r;
          float v = acc[mi][ni][r];
          float p = __shfl_xor(v, 1, 64);   // RoPE partner (d ^ 1)
          if (n >= nc) {
            float sv, cv;
            __sincosf((float)(n - nc) * invf, &sv, &cv);
            v = v * cv + sgn * p * sv;
          }
          dst[(((size_t)(b * HH + h) * NN + n) << 6) + d] = (half_t)(v * qscale);
        }
    }
  } else {
    // V: per-wave 64x64 transpose through LDS -> (B,H,D,N)
    __syncthreads();   // all waves done reading sm.s (union overwrite)
#pragma unroll
    for (int ni = 0; ni < 4; ++ni)
#pragma unroll
      for (int mi = 0; mi < 4; ++mi)
#pragma unroll
        for (int r = 0; r < 4; ++r)
          sm.T[wave][(ni * 16 + L15) * 68 + mi * 16 + quad * 4 + r] = (half_t)acc[mi][ni][r];
    __syncthreads();
    const int h = ((f0 + wn) >> 6) & 7;
    const size_t gbase = ((size_t)(b * HH + h) * DD + lane) * NN + n_base;
#pragma unroll
    for (int c = 0; c < 8; ++c)
      *(half8*)(Vt + gbase + c * 8) = *(const half8*)&sm.T[wave][lane * 68 + c * 8];
  }
}

// ---------------------------------------------------------------------------
// Kernel 2: flash attention, swapped-operand 32x32x16 MFMA.
//  - S' = K.Q^T via mfma(Kfrag, Qfrag): lane holds P[q=lane&31][16 k-values],
//    so softmax + P->A-fragment repack are fully in-register
//    (pack to half2, one shfl_xor(32) + cndmask per word). No Ps LDS.
//  - K/V staged with global_load_lds (16B), XOR-swizzled slots (slot ^= row&7)
//    via pre-swizzled global source addrs; double-buffered -> ONE barrier/tile.
//  - mask via broadcast float4 loads (L1-resident), fixed-offset exp2.
//  LDS ops/wave-tile: 16 ds_read_b128 (was 20 reads + 36 writes).
// ---------------------------------------------------------------------------
#define EXP2_OFF 4.3280851f   // 3 * log2(e)
__global__ __launch_bounds__(256, 4) void flash_mfma_kernel(
    const half_t* __restrict__ Qh,   // (B,H,N,D)  (q pre-scaled by 0.125*log2e)
    const half_t* __restrict__ Kh,   // (B,H,N,D)
    const half_t* __restrict__ Vt,   // (B,H,D,N)
    const float*  __restrict__ mask, // (B,N)
    half_t* __restrict__ O)          // (B,N,C) fp16
{
  __shared__ half_t KV[2][2][64 * 64];   // [buf][K|V][row*64 + e]  32 KB

  const int tid  = threadIdx.x;
  const int wave = tid >> 6;            // 0..3
  const int lane = tid & 63;
  const int l31  = lane & 31;
  const int hi   = lane >> 5;           // 0/1
  const int l7   = lane & 7;

  // XCD-aware decode: blocks with the same head share blockIdx%8 (same XCD)
  const int bid  = blockIdx.x;          // 0..1023
  const int xcd  = bid & 7;
  const int slot = bid >> 3;            // 0..127
  const int qt   = slot & 15;           // 16 q-tiles of 128 rows
  const int head = (slot >> 4) * 8 + xcd;   // 0..63
  const int b    = head >> 3;
  const int h    = head & 7;

  const half_t* Kt_base = Kh + ((((size_t)b * HH + h) * NN) << 6);
  const half_t* Vt_base = Vt + (((size_t)b * HH + h) * DD) * NN;

  // Q B-fragments: n = q = qt*128 + wave*32 + l31 ; k-dim elem = kd*16 + hi*8 + j
  half8 qf[4];
  {
    const half_t* Qp =
        Qh + ((((size_t)b * HH + h) * NN + qt * 128 + wave * 32 + l31) << 6) + hi * 8;
#pragma unroll
    for (int kd = 0; kd < 4; ++kd) qf[kd] = *(const half8*)(Qp + kd * 16);
  }

  // staging source pointers, pre-swizzled: LDS linear slot sl of row holds
  // source 16B-group (sl ^ (row&7)); row&7 == lane>>3 here.
  const int r8  = lane >> 3;                 // 0..7
  const int dof = ((l7 ^ r8) << 3);          // halfs
  const half_t* kg0 = Kt_base + (((size_t)(wave * 16 + r8)) << 6) + dof;
  const half_t* kg1 = kg0 + (8 << 6);
  const half_t* vg0 = Vt_base + (size_t)(wave * 16 + r8) * NN + dof;
  const half_t* vg1 = vg0 + (size_t)8 * NN;

  // LDS read addrs (bytes). K row = t*32+l31, V row = dt*32+l31; row&7 = l7.
  int adK[4], adV[4];
#pragma unroll
  for (int c = 0; c < 4; ++c) {
    const int sw = ((((c << 1) | hi) ^ l7) << 4);
    adK[c] = l31 * 128 + sw;
    adV[c] = 8192 + l31 * 128 + sw;
  }
  const char* L = (const char*)KV;

  floatx16 acc[2];
#pragma unroll
  for (int dt = 0; dt < 2; ++dt)
#pragma unroll
    for (int r = 0; r < 16; ++r) acc[dt][r] = 0.f;
  float l_part = 0.f;

  const float* mkb = mask + (size_t)b * NN + hi * 4;

  // prologue: stage tile 0 into buf 0
  gld16(kg0, &KV[0][0][wave * 1024]);
  gld16(kg1, &KV[0][0][wave * 1024 + 512]);
  gld16(vg0, &KV[0][1][wave * 1024]);
  gld16(vg1, &KV[0][1][wave * 1024 + 512]);
  __syncthreads();

#pragma unroll 1
  for (int kt = 0; kt < NN / 64; ++kt) {
    // stage next tile into the other buffer (drained by end-of-iter barrier)
    if (kt != NN / 64 - 1) {
      kg0 += 4096; kg1 += 4096; vg0 += 64; vg1 += 64;
      const int nb = (kt & 1) ^ 1;
      gld16(kg0, &KV[nb][0][wave * 1024]);
      gld16(kg1, &KV[nb][0][wave * 1024 + 512]);
      gld16(vg0, &KV[nb][1][wave * 1024]);
      gld16(vg1, &KV[nb][1][wave * 1024 + 512]);
    }

#pragma unroll
    for (int t = 0; t < 2; ++t) {
      // mask values for this lane's 16 k-slots: k = t*32 + r2*8 + hi*4 + e
      fx4 m4[4];
#pragma unroll
      for (int r2 = 0; r2 < 4; ++r2)
        m4[r2] = *(const fx4*)(mkb + t * 32 + r2 * 8);

      // S' = K.Q^T : col = q = lane&31, row = k = t*32 + (r&3)+8*(r>>2)+4*hi
      floatx16 S;
#pragma unroll
      for (int r = 0; r < 16; ++r) S[r] = 0.f;
#pragma unroll
      for (int kd = 0; kd < 4; ++kd) {
        half8 kf = *(const half8*)(L + (adK[kd] + t * 4096));
        S = __builtin_amdgcn_mfma_f32_32x32x16_f16(kf, qf[kd], S, 0, 0, 0);
      }

      // p = exp2(S + mask_k*log2e - OFF); per-q l partial (own column only)
#pragma unroll
      for (int r = 0; r < 16; ++r) {
        float p = __builtin_amdgcn_exp2f(fmaf(m4[r >> 2][r & 3], LOG2E, S[r] - EXP2_OFF));
        l_part += p;
        S[r] = p;
      }

      // pack pairs (consecutive k) to half2 words: W[r2][u] covers k =
      // t*32 + 8*r2 + 4*hi + 2u + {0,1}
      unsigned W[4][2];
#pragma unroll
      for (int r2 = 0; r2 < 4; ++r2)
#pragma unroll
        for (int u = 0; u < 2; ++u) {
          union { half_t hh[2]; unsigned w; } pk;
          pk.hh[0] = (half_t)S[r2 * 4 + 2 * u];
          pk.hh[1] = (half_t)S[r2 * 4 + 2 * u + 1];
          W[r2][u] = pk.w;
        }

      // route to PV A-fragments: pa[ks] word w = W[2*(ks&1)+hi][w&1] from
      // lane-half hi' = w>>1  ->  own + shfl_xor(32) partner, cndmask by hi
#pragma unroll
      for (int ksl = 0; ksl < 2; ++ksl) {
        unsigned A0 = W[2 * ksl][0],     A1 = W[2 * ksl][1];
        unsigned B0 = W[2 * ksl + 1][0], B1 = W[2 * ksl + 1][1];
        unsigned pA0 = __shfl_xor(A0, 32, 64), pA1 = __shfl_xor(A1, 32, 64);
        unsigned pB0 = __shfl_xor(B0, 32, 64), pB1 = __shfl_xor(B1, 32, 64);
        union { unsigned u[4]; half8 v; } pw;
        pw.u[0] = hi ? pB0 : A0;
        pw.u[1] = hi ? pB1 : A1;
        pw.u[2] = hi ? B0 : pA0;
        pw.u[3] = hi ? B1 : pA1;
        const int ks = t * 2 + ksl;
#pragma unroll
        for (int dt = 0; dt < 2; ++dt) {
          half8 vf = *(const half8*)(L + (adV[ks] + dt * 4096));
          acc[dt] = __builtin_amdgcn_mfma_f32_32x32x16_f16(pw.v, vf, acc[dt], 0, 0, 0);
        }
      }
    }

    mkb += 64;
    __syncthreads();   // drains gld16 (vmcnt) + releases both buffers
#pragma unroll
    for (int c = 0; c < 4; ++c) { adK[c] ^= 16384; adV[c] ^= 16384; }
  }

  // l: sum the two lane-halves (each lane holds partials for q = lane&31)
  l_part += __shfl_xor(l_part, 32, 64);

  const size_t orow = (size_t)b * NN + qt * 128 + wave * 32;
#pragma unroll
  for (int r = 0; r < 16; ++r) {
    const int ql  = (r & 3) + 8 * (r >> 2) + 4 * hi;   // 0..31
    const float iv = 1.0f / __shfl(l_part, ql, 64);
    const size_t ro = ((orow + ql) << 9) + (h << 6) + l31;
    O[ro]      = (half_t)(acc[0][r] * iv);
    O[ro + 32] = (half_t)(acc[1][r] * iv);
  }
}

// ---------------------------------------------------------------------------
// Kernel 3: out = O @ W_proj^T + b_proj  (fp16 MFMA, fp32 out)  [unchanged]
// ---------------------------------------------------------------------------
__global__ __launch_bounds__(256) void proj_mfma_kernel(
    const half_t* __restrict__ Ah,   // (16384, 512) fp16
    const half_t* __restrict__ Bh,   // (512, 512) fp16
    const float* __restrict__ bias,  // (512,)
    float* __restrict__ out)         // (16384, 512)
{
  __shared__ half_t As[128 * 32];
  __shared__ half_t Bs[128 * 32];

  const int tid  = threadIdx.x;
  const int wave = tid >> 6, lane = tid & 63;
  const int L15  = lane & 15, quad = lane >> 4;
  const int wm = (wave & 1) * 64, wn = (wave >> 1) * 64;
  const int m0 = blockIdx.x * 128;
  const int f0 = blockIdx.y * 128;

  const int srow = lane >> 2;
  const int scolh = (lane & 3) * 8;
  const half_t* Ag = Ah + (size_t)(m0 + wave * 16 + srow) * CC + scolh;
  const half_t* Bg = Bh + (size_t)(f0 + wave * 16 + srow) * CC + scolh;
  half_t* Al = &As[(wave * 16) * 32];
  half_t* Bl = &Bs[(wave * 16) * 32];

  floatx4 acc[4][4];
#pragma unroll
  for (int i = 0; i < 4; ++i)
#pragma unroll
    for (int j = 0; j < 4; ++j) acc[i][j] = (floatx4){0.f, 0.f, 0.f, 0.f};

  for (int k0 = 0; k0 < CC; k0 += 32) {
    __syncthreads();
    gld16(Ag + k0,           Al);
    gld16(Ag + k0 + 64 * CC, Al + 64 * 32);
    gld16(Bg + k0,           Bl);
    gld16(Bg + k0 + 64 * CC, Bl + 64 * 32);
    __syncthreads();
    half8 af[4], bf[4];
#pragma unroll
    for (int mi = 0; mi < 4; ++mi)
      af[mi] = *(const half8*)&As[(wm + mi * 16 + L15) * 32 + quad * 8];
#pragma unroll
    for (int ni = 0; ni < 4; ++ni)
      bf[ni] = *(const half8*)&Bs[(wn + ni * 16 + L15) * 32 + quad * 8];
#pragma unroll
    for (int mi = 0; mi < 4; ++mi)
#pragma unroll
      for (int ni = 0; ni < 4; ++ni)
        acc[mi][ni] = __builtin_amdgcn_mfma_f32_16x16x32_f16(af[mi], bf[ni], acc[mi][ni], 0, 0, 0);
  }

#pragma unroll
  for (int ni = 0; ni < 4; ++ni) {
    const int f = f0 + wn + ni * 16 + L15;
    const float bv = bias[f];
#pragma unroll
    for (int mi = 0; mi < 4; ++mi)
#pragma unroll
      for (int r = 0; r < 4; ++r)
        out[(size_t)(m0 + wm + mi * 16 + quad * 4 + r) * CC + f] = acc[mi][ni][r] + bv;
  }
}

// ---------------------------------------------------------------------------
extern "C" void kernel_launch(void* const* d_in, const int* in_sizes, int n_in,
                              void* d_out, int out_size, void* d_ws, size_t ws_size,
                              hipStream_t stream) {
  const float* x     = (const float*)d_in[0];
  const float* mask  = (const float*)d_in[1];
  const float* Wqkv  = (const float*)d_in[2];
  const float* Wproj = (const float*)d_in[3];
  const float* bproj = (const float*)d_in[4];
  const int*   ncp   = (const int*)d_in[5];
  float* out = (float*)d_out;

  const size_t per = (size_t)BB * HH * NN * DD;   // 8,388,608
  half_t* xh  = (half_t*)d_ws;
  half_t* Wqh = xh + (size_t)MM * CC;
  half_t* Wph = Wqh + (size_t)FF * CC;
  half_t* Qh  = Wph + (size_t)CC * CC;
  half_t* Kh  = Qh + per;
  half_t* Vt  = Kh + per;
  half_t* Oh  = Vt + per;

  cvt_kernel<<<dim3(MM * CC / 8 / 256), 256, 0, stream>>>(x, xh, MM * CC / 8);
  cvt_kernel<<<dim3(FF * CC / 8 / 256), 256, 0, stream>>>(Wqkv, Wqh, FF * CC / 8);
  cvt_kernel<<<dim3(CC * CC / 8 / 256), 256, 0, stream>>>(Wproj, Wph, CC * CC / 8);

  qkv_mfma_kernel<<<dim3(MM / 128, FF / 128), 256, 0, stream>>>(xh, Wqh, ncp, Qh, Kh, Vt);
  flash_mfma_kernel<<<dim3(BB * HH * (NN / 128)), 256, 0, stream>>>(Qh, Kh, Vt, mask, Oh);
  proj_mfma_kernel<<<dim3(MM / 128, CC / 128), 256, 0, stream>>>(Oh, Wph, bproj, out);
}

// Round 2
// 270.824 us; speedup vs baseline: 1.0366x; 1.0366x over previous
//
#include <hip/hip_runtime.h>
#include <cmath>

#define BB 8
#define NN 2048
#define CC 512
#define HH 8
#define DD 64
#define FF 1536
#define MM (BB*NN)   // 16384

typedef _Float16 half_t;
typedef __attribute__((ext_vector_type(8))) _Float16 half8;
typedef __attribute__((ext_vector_type(4))) _Float16 half4;
typedef __attribute__((ext_vector_type(4))) float floatx4;
typedef __attribute__((ext_vector_type(16))) float floatx16;
typedef __attribute__((ext_vector_type(4))) float fx4;

#define LOG2E 1.44269504088896f

// async global->LDS, 16 B per lane; LDS dest must be wave-uniform base (+lane*16)
typedef const __attribute__((address_space(1))) unsigned int* gas_ptr;
typedef __attribute__((address_space(3))) unsigned int* las_ptr;
__device__ __forceinline__ void gld16(const half_t* g, half_t* l) {
  __builtin_amdgcn_global_load_lds((gas_ptr)g, (las_ptr)l, 16, 0, 0);
}

// ---------------------------------------------------------------------------
// fp32 -> fp16 convert (8 elems/thread)
// ---------------------------------------------------------------------------
__global__ __launch_bounds__(256) void cvt_kernel(
    const float* __restrict__ s, half_t* __restrict__ d, int n8) {
  int i = blockIdx.x * 256 + threadIdx.x;
  if (i < n8) {
    float4 a = ((const float4*)s)[i * 2], b = ((const float4*)s)[i * 2 + 1];
    half8 h;
    h[0] = (half_t)a.x; h[1] = (half_t)a.y; h[2] = (half_t)a.z; h[3] = (half_t)a.w;
    h[4] = (half_t)b.x; h[5] = (half_t)b.y; h[6] = (half_t)b.z; h[7] = (half_t)b.w;
    ((half8*)d)[i] = h;
  }
}

// ---------------------------------------------------------------------------
// Kernel 1: qkv = x @ W_qkv^T  (fp16 MFMA, 128x128 tile, BK=32, 4 waves)
// Fused epilogue: RoPE (+ q scale incl. log2e) -> Qh/Kh fp16 (B,H,N,D);
// V -> LDS transpose -> Vt fp16 (B,H,D,N).   [unchanged this round]
// ---------------------------------------------------------------------------
__global__ __launch_bounds__(256) void qkv_mfma_kernel(
    const half_t* __restrict__ Ah,   // (16384, 512)
    const half_t* __restrict__ Bh,   // (1536, 512)
    const int*   __restrict__ ncp,
    half_t* __restrict__ Qh, half_t* __restrict__ Kh, half_t* __restrict__ Vt)
{
  __shared__ union {
    struct { half_t A[128 * 32]; half_t B[128 * 32]; } s;   // 16 KB
    half_t T[4][64 * 68];                                   // 34.8 KB (V epilogue)
  } sm;

  const int tid  = threadIdx.x;
  const int wave = tid >> 6, lane = tid & 63;
  const int L15  = lane & 15, quad = lane >> 4;
  const int wm = (wave & 1) * 64, wn = (wave >> 1) * 64;
  const int m0 = blockIdx.x * 128;
  const int f0 = blockIdx.y * 128;

  const int srow = lane >> 2;            // 0..15
  const int scolh = (lane & 3) * 8;      // half offset within row
  const half_t* Ag = Ah + (size_t)(m0 + wave * 16 + srow) * CC + scolh;
  const half_t* Bg = Bh + (size_t)(f0 + wave * 16 + srow) * CC + scolh;
  half_t* Al = &sm.s.A[(wave * 16) * 32];
  half_t* Bl = &sm.s.B[(wave * 16) * 32];

  floatx4 acc[4][4];
#pragma unroll
  for (int i = 0; i < 4; ++i)
#pragma unroll
    for (int j = 0; j < 4; ++j) acc[i][j] = (floatx4){0.f, 0.f, 0.f, 0.f};

  for (int k0 = 0; k0 < CC; k0 += 32) {
    __syncthreads();
    gld16(Ag + k0,            Al);
    gld16(Ag + k0 + 64 * CC,  Al + 64 * 32);
    gld16(Bg + k0,            Bl);
    gld16(Bg + k0 + 64 * CC,  Bl + 64 * 32);
    __syncthreads();
    half8 af[4], bf[4];
#pragma unroll
    for (int mi = 0; mi < 4; ++mi)
      af[mi] = *(const half8*)&sm.s.A[(wm + mi * 16 + L15) * 32 + quad * 8];
#pragma unroll
    for (int ni = 0; ni < 4; ++ni)
      bf[ni] = *(const half8*)&sm.s.B[(wn + ni * 16 + L15) * 32 + quad * 8];
#pragma unroll
    for (int mi = 0; mi < 4; ++mi)
#pragma unroll
      for (int ni = 0; ni < 4; ++ni)
        acc[mi][ni] = __builtin_amdgcn_mfma_f32_16x16x32_f16(af[mi], bf[ni], acc[mi][ni], 0, 0, 0);
  }

  const int which = f0 >> 9;         // block-uniform (128 | 512)
  const int b     = m0 >> 11;        // block-uniform
  const int n_base = (m0 & 2047) + wm;

  if (which < 2) {
    const int nc = *ncp;
    half_t* dst = which ? Kh : Qh;
    const float qscale = which ? 1.0f : (0.125f * LOG2E);
#pragma unroll
    for (int ni = 0; ni < 4; ++ni) {
      const int f = f0 + wn + ni * 16 + L15;
      const int h = (f >> 6) & 7;
      const int d = f & 63;
      const float invf = __powf(10000.0f, -(float)(d & ~1) * (1.0f / 64.0f));
      const float sgn = (d & 1) ? 1.0f : -1.0f;
#pragma unroll
      for (int mi = 0; mi < 4; ++mi)
#pragma unroll
        for (int r = 0; r < 4; ++r) {
          const int n = n_base + mi * 16 + quad * 4 + r;
          float v = acc[mi][ni][r];
          float p = __shfl_xor(v, 1, 64);   // RoPE partner (d ^ 1)
          if (n >= nc) {
            float sv, cv;
            __sincosf((float)(n - nc) * invf, &sv, &cv);
            v = v * cv + sgn * p * sv;
          }
          dst[(((size_t)(b * HH + h) * NN + n) << 6) + d] = (half_t)(v * qscale);
        }
    }
  } else {
    // V: per-wave 64x64 transpose through LDS -> (B,H,D,N)
    __syncthreads();   // all waves done reading sm.s (union overwrite)
#pragma unroll
    for (int ni = 0; ni < 4; ++ni)
#pragma unroll
      for (int mi = 0; mi < 4; ++mi)
#pragma unroll
        for (int r = 0; r < 4; ++r)
          sm.T[wave][(ni * 16 + L15) * 68 + mi * 16 + quad * 4 + r] = (half_t)acc[mi][ni][r];
    __syncthreads();
    const int h = ((f0 + wn) >> 6) & 7;
    const size_t gbase = ((size_t)(b * HH + h) * DD + lane) * NN + n_base;
#pragma unroll
    for (int c = 0; c < 8; ++c)
      *(half8*)(Vt + gbase + c * 8) = *(const half8*)&sm.T[wave][lane * 68 + c * 8];
  }
}

// ---------------------------------------------------------------------------
// Kernel 2: flash attention, swapped-operand 32x32x16 MFMA.
// This round: T3/T4 counted-vmcnt pipeline. Per tile:
//   COMPUTE(c) -> s_barrier (reads done) -> stage(kt+2 -> buf c)
//   -> s_waitcnt vmcnt(4) (waits ONLY for stage(kt+1); fresh 4 loads stay
//      in flight across the barrier) -> s_barrier -> next tile.
// Loop unrolled x2 so buffer/t offsets are ds_read immediates.
// s_setprio(1) around MFMA clusters (T5). sched_barrier(0) pins phases.
// ---------------------------------------------------------------------------
#define EXP2_OFF 4.3280851f   // 3 * log2(e)
__global__ __launch_bounds__(256, 4) void flash_mfma_kernel(
    const half_t* __restrict__ Qh,   // (B,H,N,D)  (q pre-scaled by 0.125*log2e)
    const half_t* __restrict__ Kh,   // (B,H,N,D)
    const half_t* __restrict__ Vt,   // (B,H,D,N)
    const float*  __restrict__ mask, // (B,N)
    half_t* __restrict__ O)          // (B,N,C) fp16
{
  __shared__ half_t KV[2][2][64 * 64];   // [buf][K|V][row*64 + e]  32 KB

  const int tid  = threadIdx.x;
  const int wave = tid >> 6;            // 0..3
  const int lane = tid & 63;
  const int l31  = lane & 31;
  const int hi   = lane >> 5;           // 0/1
  const int l7   = lane & 7;

  // XCD-aware decode: blocks with the same head share blockIdx%8 (same XCD)
  const int bid  = blockIdx.x;          // 0..1023
  const int xcd  = bid & 7;
  const int slot = bid >> 3;            // 0..127
  const int qt   = slot & 15;           // 16 q-tiles of 128 rows
  const int head = (slot >> 4) * 8 + xcd;   // 0..63
  const int b    = head >> 3;
  const int h    = head & 7;

  const half_t* Kt_base = Kh + ((((size_t)b * HH + h) * NN) << 6);
  const half_t* Vt_base = Vt + (((size_t)b * HH + h) * DD) * NN;

  // Q B-fragments: n = q = qt*128 + wave*32 + l31 ; k-dim elem = kd*16 + hi*8 + j
  half8 qf[4];
  {
    const half_t* Qp =
        Qh + ((((size_t)b * HH + h) * NN + qt * 128 + wave * 32 + l31) << 6) + hi * 8;
#pragma unroll
    for (int kd = 0; kd < 4; ++kd) qf[kd] = *(const half8*)(Qp + kd * 16);
  }

  // staging source pointers, pre-swizzled: LDS linear slot sl of row holds
  // source 16B-group (sl ^ (row&7)); row&7 == lane>>3 here.
  const int r8  = lane >> 3;                 // 0..7
  const int dof = ((l7 ^ r8) << 3);          // halfs
  const half_t* kbase = Kt_base + (((size_t)(wave * 16 + r8)) << 6) + dof;
  const half_t* vbase = Vt_base + (size_t)(wave * 16 + r8) * NN + dof;

  // LDS read addrs (bytes), buffer/t offsets added as immediates at use.
  int adK[4], adV[4];
#pragma unroll
  for (int c = 0; c < 4; ++c) {
    adK[c] = l31 * 128 + ((((c << 1) | hi) ^ l7) << 4);
    adV[c] = 8192 + l31 * 128 + ((((c << 1) | hi) ^ l7) << 4);
  }
  const char* L = (const char*)KV;

  floatx16 acc[2];
#pragma unroll
  for (int dt = 0; dt < 2; ++dt)
#pragma unroll
    for (int r = 0; r < 16; ++r) acc[dt][r] = 0.f;
  float l_part = 0.f;

  const float* mkb = mask + (size_t)b * NN + hi * 4;

#define STAGE(c, koff, voff)                                                  \
  {                                                                           \
    gld16(kbase + (koff),          &KV[c][0][wave * 1024]);                   \
    gld16(kbase + (koff) + 512,    &KV[c][0][wave * 1024 + 512]);             \
    gld16(vbase + (voff),          &KV[c][1][wave * 1024]);                   \
    gld16(vbase + (voff) + 8 * NN, &KV[c][1][wave * 1024 + 512]);             \
  }

#define COMPUTE(c, moff)                                                      \
  _Pragma("unroll")                                                           \
  for (int t = 0; t < 2; ++t) {                                               \
    fx4 m4[4];                                                                \
    _Pragma("unroll")                                                         \
    for (int r2 = 0; r2 < 4; ++r2)                                            \
      m4[r2] = *(const fx4*)(mkb + (moff) + t * 32 + r2 * 8);                 \
    floatx16 S;                                                               \
    _Pragma("unroll") for (int r = 0; r < 16; ++r) S[r] = 0.f;                \
    __builtin_amdgcn_s_setprio(1);                                            \
    _Pragma("unroll")                                                         \
    for (int kd = 0; kd < 4; ++kd) {                                          \
      half8 kf = *(const half8*)(L + (adK[kd] + (c) * 16384 + t * 4096));     \
      S = __builtin_amdgcn_mfma_f32_32x32x16_f16(kf, qf[kd], S, 0, 0, 0);     \
    }                                                                         \
    __builtin_amdgcn_s_setprio(0);                                            \
    _Pragma("unroll")                                                         \
    for (int r = 0; r < 16; ++r) {                                            \
      float p = __builtin_amdgcn_exp2f(fmaf(m4[r >> 2][r & 3], LOG2E, S[r] - EXP2_OFF)); \
      l_part += p;                                                            \
      S[r] = p;                                                               \
    }                                                                         \
    unsigned W[4][2];                                                         \
    _Pragma("unroll")                                                         \
    for (int r2 = 0; r2 < 4; ++r2)                                            \
      _Pragma("unroll")                                                       \
      for (int u = 0; u < 2; ++u) {                                           \
        union { half_t hh[2]; unsigned w; } pk;                               \
        pk.hh[0] = (half_t)S[r2 * 4 + 2 * u];                                 \
        pk.hh[1] = (half_t)S[r2 * 4 + 2 * u + 1];                             \
        W[r2][u] = pk.w;                                                      \
      }                                                                       \
    _Pragma("unroll")                                                         \
    for (int ksl = 0; ksl < 2; ++ksl) {                                       \
      unsigned A0 = W[2 * ksl][0],     A1 = W[2 * ksl][1];                    \
      unsigned B0 = W[2 * ksl + 1][0], B1 = W[2 * ksl + 1][1];                \
      unsigned pA0 = __shfl_xor(A0, 32, 64), pA1 = __shfl_xor(A1, 32, 64);    \
      unsigned pB0 = __shfl_xor(B0, 32, 64), pB1 = __shfl_xor(B1, 32, 64);    \
      union { unsigned u4[4]; half8 v; } pw;                                  \
      pw.u4[0] = hi ? pB0 : A0;                                               \
      pw.u4[1] = hi ? pB1 : A1;                                               \
      pw.u4[2] = hi ? B0 : pA0;                                               \
      pw.u4[3] = hi ? B1 : pA1;                                               \
      const int ks = t * 2 + ksl;                                             \
      __builtin_amdgcn_s_setprio(1);                                          \
      _Pragma("unroll")                                                       \
      for (int dt = 0; dt < 2; ++dt) {                                        \
        half8 vf = *(const half8*)(L + (adV[ks] + (c) * 16384 + dt * 4096));  \
        acc[dt] = __builtin_amdgcn_mfma_f32_32x32x16_f16(pw.v, vf, acc[dt], 0, 0, 0); \
      }                                                                       \
      __builtin_amdgcn_s_setprio(0);                                          \
    }                                                                         \
  }

  // prologue: stage tiles 0 and 1; wait only for tile 0; barrier.
  STAGE(0, 0, 0)
  STAGE(1, 4096, 64)
  asm volatile("s_waitcnt vmcnt(4)");
  __builtin_amdgcn_s_barrier();
  __builtin_amdgcn_sched_barrier(0);
  kbase += 8192; vbase += 128;   // now pointing at tile 2

#pragma unroll 1
  for (int kt2 = 0; kt2 < 15; ++kt2) {   // tiles 0..29; stages tiles 2..31
    COMPUTE(0, 0)
    __builtin_amdgcn_sched_barrier(0);
    __builtin_amdgcn_s_barrier();        // all waves done reading buf 0
    STAGE(0, 0, 0)                       // tile 2*kt2+2 -> buf 0
    asm volatile("s_waitcnt vmcnt(4)");  // stage(2*kt2+1) landed; fresh 4 in flight
    __builtin_amdgcn_s_barrier();
    __builtin_amdgcn_sched_barrier(0);

    COMPUTE(1, 64)
    __builtin_amdgcn_sched_barrier(0);
    __builtin_amdgcn_s_barrier();        // all waves done reading buf 1
    STAGE(1, 4096, 64)                   // tile 2*kt2+3 -> buf 1
    asm volatile("s_waitcnt vmcnt(4)");  // stage(2*kt2+2) landed
    __builtin_amdgcn_s_barrier();
    __builtin_amdgcn_sched_barrier(0);

    kbase += 8192; vbase += 128;
    mkb += 128;
  }

  // tail: tiles 30 (buf 0) and 31 (buf 1); no more staging
  COMPUTE(0, 0)
  asm volatile("s_waitcnt vmcnt(0)");    // stage(31) fully landed
  __builtin_amdgcn_s_barrier();
  __builtin_amdgcn_sched_barrier(0);
  COMPUTE(1, 64)

#undef STAGE
#undef COMPUTE

  // l: sum the two lane-halves (each lane holds partials for q = lane&31)
  l_part += __shfl_xor(l_part, 32, 64);

  const size_t orow = (size_t)b * NN + qt * 128 + wave * 32;
#pragma unroll
  for (int r = 0; r < 16; ++r) {
    const int ql  = (r & 3) + 8 * (r >> 2) + 4 * hi;   // 0..31
    const float iv = 1.0f / __shfl(l_part, ql, 64);
    const size_t ro = ((orow + ql) << 9) + (h << 6) + l31;
    O[ro]      = (half_t)(acc[0][r] * iv);
    O[ro + 32] = (half_t)(acc[1][r] * iv);
  }
}

// ---------------------------------------------------------------------------
// Kernel 3: out = O @ W_proj^T + b_proj  (fp16 MFMA, fp32 out)  [unchanged]
// ---------------------------------------------------------------------------
__global__ __launch_bounds__(256) void proj_mfma_kernel(
    const half_t* __restrict__ Ah,   // (16384, 512) fp16
    const half_t* __restrict__ Bh,   // (512, 512) fp16
    const float* __restrict__ bias,  // (512,)
    float* __restrict__ out)         // (16384, 512)
{
  __shared__ half_t As[128 * 32];
  __shared__ half_t Bs[128 * 32];

  const int tid  = threadIdx.x;
  const int wave = tid >> 6, lane = tid & 63;
  const int L15  = lane & 15, quad = lane >> 4;
  const int wm = (wave & 1) * 64, wn = (wave >> 1) * 64;
  const int m0 = blockIdx.x * 128;
  const int f0 = blockIdx.y * 128;

  const int srow = lane >> 2;
  const int scolh = (lane & 3) * 8;
  const half_t* Ag = Ah + (size_t)(m0 + wave * 16 + srow) * CC + scolh;
  const half_t* Bg = Bh + (size_t)(f0 + wave * 16 + srow) * CC + scolh;
  half_t* Al = &As[(wave * 16) * 32];
  half_t* Bl = &Bs[(wave * 16) * 32];

  floatx4 acc[4][4];
#pragma unroll
  for (int i = 0; i < 4; ++i)
#pragma unroll
    for (int j = 0; j < 4; ++j) acc[i][j] = (floatx4){0.f, 0.f, 0.f, 0.f};

  for (int k0 = 0; k0 < CC; k0 += 32) {
    __syncthreads();
    gld16(Ag + k0,           Al);
    gld16(Ag + k0 + 64 * CC, Al + 64 * 32);
    gld16(Bg + k0,           Bl);
    gld16(Bg + k0 + 64 * CC, Bl + 64 * 32);
    __syncthreads();
    half8 af[4], bf[4];
#pragma unroll
    for (int mi = 0; mi < 4; ++mi)
      af[mi] = *(const half8*)&As[(wm + mi * 16 + L15) * 32 + quad * 8];
#pragma unroll
    for (int ni = 0; ni < 4; ++ni)
      bf[ni] = *(const half8*)&Bs[(wn + ni * 16 + L15) * 32 + quad * 8];
#pragma unroll
    for (int mi = 0; mi < 4; ++mi)
#pragma unroll
      for (int ni = 0; ni < 4; ++ni)
        acc[mi][ni] = __builtin_amdgcn_mfma_f32_16x16x32_f16(af[mi], bf[ni], acc[mi][ni], 0, 0, 0);
  }

#pragma unroll
  for (int ni = 0; ni < 4; ++ni) {
    const int f = f0 + wn + ni * 16 + L15;
    const float bv = bias[f];
#pragma unroll
    for (int mi = 0; mi < 4; ++mi)
#pragma unroll
      for (int r = 0; r < 4; ++r)
        out[(size_t)(m0 + wm + mi * 16 + quad * 4 + r) * CC + f] = acc[mi][ni][r] + bv;
  }
}

// ---------------------------------------------------------------------------
extern "C" void kernel_launch(void* const* d_in, const int* in_sizes, int n_in,
                              void* d_out, int out_size, void* d_ws, size_t ws_size,
                              hipStream_t stream) {
  const float* x     = (const float*)d_in[0];
  const float* mask  = (const float*)d_in[1];
  const float* Wqkv  = (const float*)d_in[2];
  const float* Wproj = (const float*)d_in[3];
  const float* bproj = (const float*)d_in[4];
  const int*   ncp   = (const int*)d_in[5];
  float* out = (float*)d_out;

  const size_t per = (size_t)BB * HH * NN * DD;   // 8,388,608
  half_t* xh  = (half_t*)d_ws;
  half_t* Wqh = xh + (size_t)MM * CC;
  half_t* Wph = Wqh + (size_t)FF * CC;
  half_t* Qh  = Wph + (size_t)CC * CC;
  half_t* Kh  = Qh + per;
  half_t* Vt  = Kh + per;
  half_t* Oh  = Vt + per;

  cvt_kernel<<<dim3(MM * CC / 8 / 256), 256, 0, stream>>>(x, xh, MM * CC / 8);
  cvt_kernel<<<dim3(FF * CC / 8 / 256), 256, 0, stream>>>(Wqkv, Wqh, FF * CC / 8);
  cvt_kernel<<<dim3(CC * CC / 8 / 256), 256, 0, stream>>>(Wproj, Wph, CC * CC / 8);

  qkv_mfma_kernel<<<dim3(MM / 128, FF / 128), 256, 0, stream>>>(xh, Wqh, ncp, Qh, Kh, Vt);
  flash_mfma_kernel<<<dim3(BB * HH * (NN / 128)), 256, 0, stream>>>(Qh, Kh, Vt, mask, Oh);
  proj_mfma_kernel<<<dim3(MM / 128, CC / 128), 256, 0, stream>>>(Oh, Wph, bproj, out);
}